// Round 10
// baseline (171.326 us; speedup 1.0000x reference)
//
#include <hip/hip_runtime.h>

// FeatureRestrain: mask[b,c] = (mean(in[b,c,:,:]) >= kth_largest_b) ? 0.8 : 1.2
// in: [64, 2048, 14, 14] f32; out: [64, 2048] f32; k = 1638.
//
// ROUND 10 = RESUBMIT of round-9 MEASUREMENT PROBE (round 9 never acquired a
// GPU). Kernels byte-identical to round 8; gap_kernel launched TWICE
// (idempotent: second launch rewrites identical keys).
//   gap_time = dur_us(probe) - dur_us(R8=154.5) - launch_gap
// Distinguishes: (A) gap ~50us (more optimization headroom) vs (B) harness
// reset dominates dur_us and gap is already ~20us (near floor).

constexpr int B = 64;
constexpr int C = 2048;
constexpr int HW4 = 49;            // 196 floats = 49 float4 per channel
constexpr int TARGET = 410;        // C - k: 0-based ascending index of k-th largest
constexpr float ALPHA = 0.8f;
constexpr float BETA = 1.2f;

constexpr int GAP_BLOCKS = 2048;
constexpr int GAP_THREADS = 256;
constexpr int NWAVES = GAP_BLOCKS * GAP_THREADS / 64;   // 8192
constexpr int CH_PER_WAVE = (B * C) / NWAVES;           // 16

// Monotone map f32 -> u32 (ascending order preserved)
__device__ __forceinline__ unsigned f2key(float f) {
    unsigned b = __float_as_uint(f);
    return (b & 0x80000000u) ? ~b : (b | 0x80000000u);
}

__device__ __forceinline__ float hsum4(float4 v) {
    return (v.x + v.y) + (v.z + v.w);
}

__global__ __launch_bounds__(256) void gap_kernel(
        const float* __restrict__ in, unsigned* __restrict__ keys_out) {
    const int wave = (blockIdx.x * blockDim.x + threadIdx.x) >> 6;
    const int lane = threadIdx.x & 63;
    const float4* __restrict__ in4 = reinterpret_cast<const float4*>(in);

    const int ch_base = wave * CH_PER_WAVE;
    const float4 zero = make_float4(0.f, 0.f, 0.f, 0.f);

    #pragma unroll
    for (int half = 0; half < 2; ++half) {
        const int cb = ch_base + half * 8;
        float4 v0 = (lane < HW4) ? in4[(size_t)(cb + 0) * HW4 + lane] : zero;
        float4 v1 = (lane < HW4) ? in4[(size_t)(cb + 1) * HW4 + lane] : zero;
        float4 v2 = (lane < HW4) ? in4[(size_t)(cb + 2) * HW4 + lane] : zero;
        float4 v3 = (lane < HW4) ? in4[(size_t)(cb + 3) * HW4 + lane] : zero;
        float4 v4 = (lane < HW4) ? in4[(size_t)(cb + 4) * HW4 + lane] : zero;
        float4 v5 = (lane < HW4) ? in4[(size_t)(cb + 5) * HW4 + lane] : zero;
        float4 v6 = (lane < HW4) ? in4[(size_t)(cb + 6) * HW4 + lane] : zero;
        float4 v7 = (lane < HW4) ? in4[(size_t)(cb + 7) * HW4 + lane] : zero;

        float s0 = hsum4(v0), s1 = hsum4(v1), s2 = hsum4(v2), s3 = hsum4(v3);
        float s4 = hsum4(v4), s5 = hsum4(v5), s6 = hsum4(v6), s7 = hsum4(v7);
        #pragma unroll
        for (int off = 32; off >= 1; off >>= 1) {
            s0 += __shfl_xor(s0, off, 64);
            s1 += __shfl_xor(s1, off, 64);
            s2 += __shfl_xor(s2, off, 64);
            s3 += __shfl_xor(s3, off, 64);
            s4 += __shfl_xor(s4, off, 64);
            s5 += __shfl_xor(s5, off, 64);
            s6 += __shfl_xor(s6, off, 64);
            s7 += __shfl_xor(s7, off, 64);
        }
        if (lane == 0) {
            const float inv = 1.0f / 196.0f;
            keys_out[cb + 0] = f2key(s0 * inv);
            keys_out[cb + 1] = f2key(s1 * inv);
            keys_out[cb + 2] = f2key(s2 * inv);
            keys_out[cb + 3] = f2key(s3 * inv);
            keys_out[cb + 4] = f2key(s4 * inv);
            keys_out[cb + 5] = f2key(s5 * inv);
            keys_out[cb + 6] = f2key(s6 * inv);
            keys_out[cb + 7] = f2key(s7 * inv);
        }
    }
}

// Kernel 2: per-row exact radix select (4 passes x 8 bits) + mask write.
// Proven rounds 4/5/8 (absmax 0.0): wave-parallel 256-bin prefix scan +
// per-wave histograms; uint4 key load, float4 mask store.
__global__ __launch_bounds__(256) void select_mask_kernel(
        const unsigned* __restrict__ keys_in, float* __restrict__ out) {
    __shared__ unsigned keys[C];
    __shared__ int hist[4][256];
    __shared__ int wsum[4];
    __shared__ unsigned s_prefix;
    __shared__ int s_target;

    const int b = blockIdx.x;
    const int tid = threadIdx.x;
    const int lane = tid & 63;
    const int wid = tid >> 6;
    const uint4* __restrict__ row4 =
        reinterpret_cast<const uint4*>(keys_in + (size_t)b * C);

    uint4* keys4 = reinterpret_cast<uint4*>(keys);
    #pragma unroll
    for (int i = 0; i < C / 4 / 256; ++i)
        keys4[tid + i * 256] = row4[tid + i * 256];
    if (tid == 0) { s_prefix = 0u; s_target = TARGET; }
    __syncthreads();

    #pragma unroll
    for (int pass = 0; pass < 4; ++pass) {
        const int shift = 24 - 8 * pass;
        const unsigned hi_mask = (pass == 0) ? 0u : (0xFFFFFFFFu << (shift + 8));

        #pragma unroll
        for (int w = 0; w < 4; ++w) hist[w][tid] = 0;
        const unsigned prefix = s_prefix;   // visible: barrier at end of prev pass
        const int target = s_target;
        __syncthreads();

        #pragma unroll
        for (int i = 0; i < C / 256; ++i) {
            unsigned u = keys[tid + i * 256];
            if ((u & hi_mask) == prefix)
                atomicAdd(&hist[wid][(u >> shift) & 255u], 1);
        }
        __syncthreads();

        const int h = hist[0][tid] + hist[1][tid] + hist[2][tid] + hist[3][tid];
        int inc = h;
        #pragma unroll
        for (int off = 1; off < 64; off <<= 1) {
            int n = __shfl_up(inc, off, 64);
            if (lane >= off) inc += n;
        }
        if (lane == 63) wsum[wid] = inc;
        __syncthreads();
        int woff = 0;
        #pragma unroll
        for (int w = 0; w < 4; ++w)
            if (w < wid) woff += wsum[w];
        inc += woff;
        const int exc = inc - h;
        if (exc <= target && target < inc) {   // exactly one thread matches
            s_prefix = prefix | ((unsigned)tid << shift);
            s_target = target - exc;
        }
        __syncthreads();
    }

    const unsigned thresh = s_prefix;   // exact key of the k-th largest mean
    float4* __restrict__ orow4 =
        reinterpret_cast<float4*>(out + (size_t)b * C);
    #pragma unroll
    for (int i = 0; i < C / 4 / 256; ++i) {
        const int idx = tid + i * 256;
        uint4 kq = keys4[idx];
        float4 m;
        m.x = (kq.x >= thresh) ? ALPHA : BETA;
        m.y = (kq.y >= thresh) ? ALPHA : BETA;
        m.z = (kq.z >= thresh) ? ALPHA : BETA;
        m.w = (kq.w >= thresh) ? ALPHA : BETA;
        orow4[idx] = m;
    }
}

extern "C" void kernel_launch(void* const* d_in, const int* in_sizes, int n_in,
                              void* d_out, int out_size, void* d_ws, size_t ws_size,
                              hipStream_t stream) {
    const float* in = (const float*)d_in[0];
    float* out = (float*)d_out;
    unsigned* keys = (unsigned*)d_ws;   // 64*2048*4 = 512 KB scratch

    // PROBE: gap launched twice (idempotent). dur_us(probe)-154.5 = gap cost.
    gap_kernel<<<GAP_BLOCKS, GAP_THREADS, 0, stream>>>(in, keys);
    gap_kernel<<<GAP_BLOCKS, GAP_THREADS, 0, stream>>>(in, keys);
    select_mask_kernel<<<B, 256, 0, stream>>>(keys, out);
}

// Round 11
// 154.247 us; speedup vs baseline: 1.1107x; 1.1107x over previous
//
#include <hip/hip_runtime.h>

// FeatureRestrain: mask[b,c] = (mean(in[b,c,:,:]) >= kth_largest_b) ? 0.8 : 1.2
// in: [64, 2048, 14, 14] f32; out: [64, 2048] f32; k = 1638.
//
// FINAL (round 11): revert round-10 measurement probe (double gap launch).
// Probe calibration: gap_kernel = 16.8 us for 102.76 MB => ~6.1 TB/s,
// ~90% of achievable HBM BW (harness fill kernels hit 6.7-6.9 TB/s).
// select_mask_kernel ~4 us (exact radix select, absmax 0.0 across all runs).
// Remaining ~130 us of dur_us is fixed harness reset (411 MB ws poison +
// input restore), outside kernel control.
//
// History: fused single-launch (R6) regressed 14x — per-key agent-scope
// release atomics forced an L2-writeback storm on non-coherent XCD L2s.
// Two-kernel structure is the stable optimum.

constexpr int B = 64;
constexpr int C = 2048;
constexpr int HW4 = 49;            // 196 floats = 49 float4 per channel
constexpr int TARGET = 410;        // C - k: 0-based ascending index of k-th largest
constexpr float ALPHA = 0.8f;
constexpr float BETA = 1.2f;

constexpr int GAP_BLOCKS = 2048;
constexpr int GAP_THREADS = 256;
constexpr int NWAVES = GAP_BLOCKS * GAP_THREADS / 64;   // 8192
constexpr int CH_PER_WAVE = (B * C) / NWAVES;           // 16

// Monotone map f32 -> u32 (ascending order preserved)
__device__ __forceinline__ unsigned f2key(float f) {
    unsigned b = __float_as_uint(f);
    return (b & 0x80000000u) ? ~b : (b | 0x80000000u);
}

__device__ __forceinline__ float hsum4(float4 v) {
    return (v.x + v.y) + (v.z + v.w);
}

// Kernel 1: global average pool. One wave per channel; 49 contiguous float4
// per channel; lanes 0..48 load, shfl_xor tree reduce. Measured ~6.1 TB/s.
__global__ __launch_bounds__(256) void gap_kernel(
        const float* __restrict__ in, unsigned* __restrict__ keys_out) {
    const int wave = (blockIdx.x * blockDim.x + threadIdx.x) >> 6;
    const int lane = threadIdx.x & 63;
    const float4* __restrict__ in4 = reinterpret_cast<const float4*>(in);

    const int ch_base = wave * CH_PER_WAVE;
    const float4 zero = make_float4(0.f, 0.f, 0.f, 0.f);

    #pragma unroll
    for (int half = 0; half < 2; ++half) {
        const int cb = ch_base + half * 8;
        float4 v0 = (lane < HW4) ? in4[(size_t)(cb + 0) * HW4 + lane] : zero;
        float4 v1 = (lane < HW4) ? in4[(size_t)(cb + 1) * HW4 + lane] : zero;
        float4 v2 = (lane < HW4) ? in4[(size_t)(cb + 2) * HW4 + lane] : zero;
        float4 v3 = (lane < HW4) ? in4[(size_t)(cb + 3) * HW4 + lane] : zero;
        float4 v4 = (lane < HW4) ? in4[(size_t)(cb + 4) * HW4 + lane] : zero;
        float4 v5 = (lane < HW4) ? in4[(size_t)(cb + 5) * HW4 + lane] : zero;
        float4 v6 = (lane < HW4) ? in4[(size_t)(cb + 6) * HW4 + lane] : zero;
        float4 v7 = (lane < HW4) ? in4[(size_t)(cb + 7) * HW4 + lane] : zero;

        float s0 = hsum4(v0), s1 = hsum4(v1), s2 = hsum4(v2), s3 = hsum4(v3);
        float s4 = hsum4(v4), s5 = hsum4(v5), s6 = hsum4(v6), s7 = hsum4(v7);
        #pragma unroll
        for (int off = 32; off >= 1; off >>= 1) {
            s0 += __shfl_xor(s0, off, 64);
            s1 += __shfl_xor(s1, off, 64);
            s2 += __shfl_xor(s2, off, 64);
            s3 += __shfl_xor(s3, off, 64);
            s4 += __shfl_xor(s4, off, 64);
            s5 += __shfl_xor(s5, off, 64);
            s6 += __shfl_xor(s6, off, 64);
            s7 += __shfl_xor(s7, off, 64);
        }
        if (lane == 0) {
            const float inv = 1.0f / 196.0f;
            keys_out[cb + 0] = f2key(s0 * inv);
            keys_out[cb + 1] = f2key(s1 * inv);
            keys_out[cb + 2] = f2key(s2 * inv);
            keys_out[cb + 3] = f2key(s3 * inv);
            keys_out[cb + 4] = f2key(s4 * inv);
            keys_out[cb + 5] = f2key(s5 * inv);
            keys_out[cb + 6] = f2key(s6 * inv);
            keys_out[cb + 7] = f2key(s7 * inv);
        }
    }
}

// Kernel 2: per-row exact radix select (4 passes x 8 bits) + mask write.
// Wave-parallel 256-bin prefix scan + per-wave histograms; uint4 key load,
// float4 mask store. ~4 us, absmax 0.0 across all runs.
__global__ __launch_bounds__(256) void select_mask_kernel(
        const unsigned* __restrict__ keys_in, float* __restrict__ out) {
    __shared__ unsigned keys[C];
    __shared__ int hist[4][256];
    __shared__ int wsum[4];
    __shared__ unsigned s_prefix;
    __shared__ int s_target;

    const int b = blockIdx.x;
    const int tid = threadIdx.x;
    const int lane = tid & 63;
    const int wid = tid >> 6;
    const uint4* __restrict__ row4 =
        reinterpret_cast<const uint4*>(keys_in + (size_t)b * C);

    uint4* keys4 = reinterpret_cast<uint4*>(keys);
    #pragma unroll
    for (int i = 0; i < C / 4 / 256; ++i)
        keys4[tid + i * 256] = row4[tid + i * 256];
    if (tid == 0) { s_prefix = 0u; s_target = TARGET; }
    __syncthreads();

    #pragma unroll
    for (int pass = 0; pass < 4; ++pass) {
        const int shift = 24 - 8 * pass;
        const unsigned hi_mask = (pass == 0) ? 0u : (0xFFFFFFFFu << (shift + 8));

        #pragma unroll
        for (int w = 0; w < 4; ++w) hist[w][tid] = 0;
        const unsigned prefix = s_prefix;   // visible: barrier at end of prev pass
        const int target = s_target;
        __syncthreads();

        #pragma unroll
        for (int i = 0; i < C / 256; ++i) {
            unsigned u = keys[tid + i * 256];
            if ((u & hi_mask) == prefix)
                atomicAdd(&hist[wid][(u >> shift) & 255u], 1);
        }
        __syncthreads();

        const int h = hist[0][tid] + hist[1][tid] + hist[2][tid] + hist[3][tid];
        int inc = h;
        #pragma unroll
        for (int off = 1; off < 64; off <<= 1) {
            int n = __shfl_up(inc, off, 64);
            if (lane >= off) inc += n;
        }
        if (lane == 63) wsum[wid] = inc;
        __syncthreads();
        int woff = 0;
        #pragma unroll
        for (int w = 0; w < 4; ++w)
            if (w < wid) woff += wsum[w];
        inc += woff;
        const int exc = inc - h;
        if (exc <= target && target < inc) {   // exactly one thread matches
            s_prefix = prefix | ((unsigned)tid << shift);
            s_target = target - exc;
        }
        __syncthreads();
    }

    const unsigned thresh = s_prefix;   // exact key of the k-th largest mean
    float4* __restrict__ orow4 =
        reinterpret_cast<float4*>(out + (size_t)b * C);
    #pragma unroll
    for (int i = 0; i < C / 4 / 256; ++i) {
        const int idx = tid + i * 256;
        uint4 kq = keys4[idx];
        float4 m;
        m.x = (kq.x >= thresh) ? ALPHA : BETA;
        m.y = (kq.y >= thresh) ? ALPHA : BETA;
        m.z = (kq.z >= thresh) ? ALPHA : BETA;
        m.w = (kq.w >= thresh) ? ALPHA : BETA;
        orow4[idx] = m;
    }
}

extern "C" void kernel_launch(void* const* d_in, const int* in_sizes, int n_in,
                              void* d_out, int out_size, void* d_ws, size_t ws_size,
                              hipStream_t stream) {
    const float* in = (const float*)d_in[0];
    float* out = (float*)d_out;
    unsigned* keys = (unsigned*)d_ws;   // 64*2048*4 = 512 KB scratch

    gap_kernel<<<GAP_BLOCKS, GAP_THREADS, 0, stream>>>(in, keys);
    select_mask_kernel<<<B, 256, 0, stream>>>(keys, out);
}